// Round 1
// baseline (1455.681 us; speedup 1.0000x reference)
//
#include <hip/hip_runtime.h>

#define N_NODES 200000
#define N_EDGES 6400000

constexpr int SCAN_CHUNK = 2048;                                    // 256 threads x 8
constexpr int NBLK_SCAN  = (N_NODES + SCAN_CHUNK - 1) / SCAN_CHUNK; // 98

// ---- edge index load helper: handles int32 or int64 storage ----
__device__ __forceinline__ int ld_edge(const void* ei, int is64, int idx) {
    return is64 ? (int)((const long long*)ei)[idx] : ((const int*)ei)[idx];
}

__global__ void k_zero(int* __restrict__ p, int n) {
    int stride = gridDim.x * blockDim.x;
    for (int i = blockIdx.x * blockDim.x + threadIdx.x; i < n; i += stride) p[i] = 0;
}

// int64 little-endian values < 2^31  =>  every odd u32 slot is 0
__global__ void k_detect(const unsigned int* __restrict__ ei, int* __restrict__ flag) {
    __shared__ int nz;
    if (threadIdx.x == 0) nz = 0;
    __syncthreads();
    if (ei[2 * threadIdx.x + 1] != 0u) atomicOr(&nz, 1);
    __syncthreads();
    if (threadIdx.x == 0) *flag = nz ? 0 : 1;
}

__global__ void k_count(const void* __restrict__ ei, const int* __restrict__ flag,
                        int* __restrict__ cnt) {
    const int is64 = *flag;
    int stride = gridDim.x * blockDim.x;
    for (int e = blockIdx.x * blockDim.x + threadIdx.x; e < N_EDGES; e += stride) {
        int d = ld_edge(ei, is64, N_EDGES + e);
        atomicAdd(&cnt[d], 1);
    }
}

__global__ void k_dinv(const int* __restrict__ cnt, float* __restrict__ dinv) {
    int stride = gridDim.x * blockDim.x;
    for (int i = blockIdx.x * blockDim.x + threadIdx.x; i < N_NODES; i += stride)
        dinv[i] = rsqrtf((float)cnt[i] + 1.0f);
}

__global__ void k_scan_bsums(const int* __restrict__ cnt, int* __restrict__ bsum) {
    __shared__ int red[256];
    int base = blockIdx.x * SCAN_CHUNK;
    int t = threadIdx.x;
    int s = 0;
    for (int k = t; k < SCAN_CHUNK; k += 256) {
        int i = base + k;
        s += (i < N_NODES) ? cnt[i] : 0;
    }
    red[t] = s;
    __syncthreads();
    for (int off = 128; off > 0; off >>= 1) {
        if (t < off) red[t] += red[t + off];
        __syncthreads();
    }
    if (t == 0) bsum[blockIdx.x] = red[0];
}

__global__ void k_scan_top(const int* __restrict__ bsum, int* __restrict__ boff) {
    __shared__ int s[128];
    int t = threadIdx.x;
    int v = (t < NBLK_SCAN) ? bsum[t] : 0;
    s[t] = v;
    __syncthreads();
    for (int off = 1; off < 128; off <<= 1) {
        int add = (t >= off) ? s[t - off] : 0;
        __syncthreads();
        s[t] += add;
        __syncthreads();
    }
    if (t < NBLK_SCAN) boff[t] = s[t] - v;  // exclusive prefix
}

__global__ void k_scan_write(const int* __restrict__ cnt, const int* __restrict__ boff,
                             int* __restrict__ rowptr, int* __restrict__ cursor) {
    __shared__ int tsum[256];
    int b = blockIdx.x, t = threadIdx.x;
    int tb = b * SCAN_CHUNK + t * 8;
    int local[8];
    int s = 0;
#pragma unroll
    for (int k = 0; k < 8; ++k) {
        int i = tb + k;
        local[k] = (i < N_NODES) ? cnt[i] : 0;
        s += local[k];
    }
    tsum[t] = s;
    __syncthreads();
    int v = s;
    for (int off = 1; off < 256; off <<= 1) {
        int add = (t >= off) ? tsum[t - off] : 0;
        __syncthreads();
        tsum[t] += add;
        __syncthreads();
    }
    int excl = tsum[t] - v + boff[b];
#pragma unroll
    for (int k = 0; k < 8; ++k) {
        int i = tb + k;
        if (i < N_NODES) { rowptr[i] = excl; cursor[i] = excl; }
        excl += local[k];
    }
    if (b == 0 && t == 0) rowptr[N_NODES] = N_EDGES;
}

__global__ void k_scatter(const void* __restrict__ ei, const int* __restrict__ flag,
                          int* __restrict__ cursor, int* __restrict__ esrc) {
    const int is64 = *flag;
    int stride = gridDim.x * blockDim.x;
    for (int e = blockIdx.x * blockDim.x + threadIdx.x; e < N_EDGES; e += stride) {
        int s = ld_edge(ei, is64, e);
        int d = ld_edge(ei, is64, N_EDGES + e);
        int pos = atomicAdd(&cursor[d], 1);
        esrc[pos] = s;
    }
}

// h = x @ W  (row-major x: [N, FIN], W: [FIN, FOUT])
template <int FIN, int FOUT>
__global__ void k_xw(const float* __restrict__ x, const float* __restrict__ W,
                     float* __restrict__ h) {
    __shared__ float sW[FIN * FOUT];
    int t = threadIdx.x;
    if (t < FIN * FOUT) sW[t] = W[t];
    __syncthreads();
    int i = blockIdx.x * blockDim.x + t;
    if (i >= N_NODES) return;
    float xi[FIN];
#pragma unroll
    for (int k = 0; k < FIN; ++k) xi[k] = x[i * FIN + k];
#pragma unroll
    for (int j = 0; j < FOUT; ++j) {
        float acc = 0.f;
#pragma unroll
        for (int k = 0; k < FIN; ++k) acc += xi[k] * sW[k * FOUT + j];
        h[i * FOUT + j] = acc;
    }
}

// 16 lanes per node, lane = feature. Atomic-free CSR gather.
template <int F, bool RELU>
__global__ void k_agg(const int* __restrict__ rowptr, const int* __restrict__ esrc,
                      const float* __restrict__ dinv, const float* __restrict__ h,
                      const float* __restrict__ bias, float* __restrict__ out) {
    int tid = blockIdx.x * blockDim.x + threadIdx.x;
    int g = tid >> 4;       // node
    int f = tid & 15;       // feature lane
    if (g >= N_NODES) return;
    float di = dinv[g];
    int e0 = rowptr[g], e1 = rowptr[g + 1];
    float acc = 0.f;
    for (int e = e0; e < e1; ++e) {
        int s = esrc[e];
        float nrm = dinv[s] * di;
        if (f < F) acc += nrm * h[s * F + f];
    }
    if (f < F) {
        float r = acc + di * di * h[g * F + f] + bias[f];
        if (RELU) r = fmaxf(r, 0.f);
        out[g * F + f] = r;
    }
}

extern "C" void kernel_launch(void* const* d_in, const int* in_sizes, int n_in,
                              void* d_out, int out_size, void* d_ws, size_t ws_size,
                              hipStream_t stream) {
    const float* x  = (const float*)d_in[0];
    const void*  ei = d_in[1];
    const float* W1 = (const float*)d_in[2];
    const float* b1 = (const float*)d_in[3];
    const float* W2 = (const float*)d_in[4];
    const float* b2 = (const float*)d_in[5];
    const float* W3 = (const float*)d_in[6];
    const float* b3 = (const float*)d_in[7];
    float* out = (float*)d_out;

    char* w = (char*)d_ws;
    int*   cnt    = (int*)(w + 0);         //   800000 B
    int*   rowptr = (int*)(w + 800000);    //   800016 B (200001 ints, padded)
    int*   cursor = (int*)(w + 1600016);   //   800000 B
    int*   bsum   = (int*)(w + 2400016);   //      512 B
    int*   boff   = (int*)(w + 2400528);   //      512 B
    int*   flag   = (int*)(w + 2401040);   //       16 B
    float* dinv   = (float*)(w + 2401056); //   800000 B
    int*   esrc   = (int*)(w + 3201056);   // 25600000 B
    float* hbuf   = (float*)(w + 28801056);// 12800000 B (200000*16 f32)
    float* gbuf   = (float*)(w + 41601056);//  8800000 B (200000*11 f32)
    // total ~50.4 MB

    // ---- build degree + CSR (shared across all 3 layers) ----
    k_zero<<<784, 256, 0, stream>>>(cnt, N_NODES);
    k_detect<<<1, 256, 0, stream>>>((const unsigned int*)ei, flag);
    k_count<<<2048, 256, 0, stream>>>(ei, flag, cnt);
    k_dinv<<<784, 256, 0, stream>>>(cnt, dinv);
    k_scan_bsums<<<NBLK_SCAN, 256, 0, stream>>>(cnt, bsum);
    k_scan_top<<<1, 128, 0, stream>>>(bsum, boff);
    k_scan_write<<<NBLK_SCAN, 256, 0, stream>>>(cnt, boff, rowptr, cursor);
    k_scatter<<<2048, 256, 0, stream>>>(ei, flag, cursor, esrc);

    // ---- layer 1: relu(gcn(x, W1, b1)) ----
    k_xw<11, 11><<<782, 256, 0, stream>>>(x, W1, hbuf);
    k_agg<11, true><<<12500, 256, 0, stream>>>(rowptr, esrc, dinv, hbuf, b1, gbuf);
    // ---- layer 2: relu(gcn(g, W2, b2)) ----
    k_xw<11, 11><<<782, 256, 0, stream>>>(gbuf, W2, hbuf);
    k_agg<11, true><<<12500, 256, 0, stream>>>(rowptr, esrc, dinv, hbuf, b2, gbuf);
    // ---- layer 3: gcn(g, W3, b3) ----
    k_xw<11, 16><<<782, 256, 0, stream>>>(gbuf, W3, hbuf);
    k_agg<16, false><<<12500, 256, 0, stream>>>(rowptr, esrc, dinv, hbuf, b3, out);
}

// Round 2
// 762.175 us; speedup vs baseline: 1.9099x; 1.9099x over previous
//
#include <hip/hip_runtime.h>

#define N_NODES 200000
#define N_EDGES 6400000

constexpr int BSHIFT = 9;                      // 512 nodes per bucket
constexpr int NBUCK  = (N_NODES + 511) / 512;  // 391
constexpr int CHUNK  = 16384;
constexpr int NCHUNK = (N_EDGES + CHUNK - 1) / CHUNK;  // 391
constexpr int MAXBUCK = 18432;                 // lambda=16384, +16 sigma

// ---- edge index load helper: handles int32 or int64 storage ----
__device__ __forceinline__ int ld_edge(const void* ei, int is64, int idx) {
    return is64 ? (int)((const long long*)ei)[idx] : ((const int*)ei)[idx];
}

__global__ void k_zero(int* __restrict__ p, int n) {
    int i = blockIdx.x * blockDim.x + threadIdx.x;
    if (i < n) p[i] = 0;
}

// int64 little-endian values < 2^31  =>  every odd u32 slot is 0
__global__ void k_detect(const unsigned int* __restrict__ ei, int* __restrict__ flag) {
    __shared__ int nz;
    if (threadIdx.x == 0) nz = 0;
    __syncthreads();
    if (ei[2 * threadIdx.x + 1] != 0u) atomicOr(&nz, 1);
    __syncthreads();
    if (threadIdx.x == 0) *flag = nz ? 0 : 1;
}

// bucket histogram: LDS-accumulated, one global atomic per bucket per block
__global__ void k_hist(const void* __restrict__ ei, const int* __restrict__ flag,
                       int* __restrict__ bucketCnt) {
    __shared__ int h[NBUCK];
    for (int i = threadIdx.x; i < NBUCK; i += 256) h[i] = 0;
    __syncthreads();
    const int is64 = *flag;
    int stride = gridDim.x * blockDim.x;
    for (int e = blockIdx.x * 256 + threadIdx.x; e < N_EDGES; e += stride) {
        int d = ld_edge(ei, is64, N_EDGES + e);
        atomicAdd(&h[d >> BSHIFT], 1);
    }
    __syncthreads();
    for (int i = threadIdx.x; i < NBUCK; i += 256)
        if (h[i]) atomicAdd(&bucketCnt[i], h[i]);
}

// single-block scan of 391 bucket counts -> exclusive bases + cursors
__global__ void k_scan_buckets(const int* __restrict__ bucketCnt,
                               int* __restrict__ bucketBase,
                               int* __restrict__ bucketCursor) {
    __shared__ int sc[512];
    int t = threadIdx.x;
    sc[t]       = (t < NBUCK)       ? bucketCnt[t]       : 0;
    sc[t + 256] = (t + 256 < NBUCK) ? bucketCnt[t + 256] : 0;
    __syncthreads();
    for (int off = 1; off < 512; off <<= 1) {
        int a0 = (t >= off) ? sc[t - off] : 0;
        int a1 = sc[t + 256 - off];
        __syncthreads();
        sc[t] += a0; sc[t + 256] += a1;
        __syncthreads();
    }
    for (int i = t; i < NBUCK; i += 256) {
        int excl = sc[i] - bucketCnt[i];
        bucketBase[i] = excl;
        bucketCursor[i] = excl;
    }
    if (t == 0) bucketBase[NBUCK] = N_EDGES;
}

// level-1: bin a 16K-edge chunk by bucket in LDS, write contiguous runs
__global__ void __launch_bounds__(256)
k_binscatter(const void* __restrict__ ei, const int* __restrict__ flag,
             int* __restrict__ bucketCursor, unsigned int* __restrict__ bin) {
    __shared__ int hist[NBUCK];
    __shared__ int pref[NBUCK + 1];
    __shared__ int cur[NBUCK];
    __shared__ int gb[NBUCK];
    __shared__ int sc[512];
    __shared__ unsigned int stage[CHUNK];
    const int is64 = *flag;
    int b = blockIdx.x, t = threadIdx.x;
    int e0 = b * CHUNK;
    int n = min(CHUNK, N_EDGES - e0);
    for (int i = t; i < NBUCK; i += 256) hist[i] = 0;
    __syncthreads();
    // pass A: per-chunk bucket histogram
    for (int i = t; i < n; i += 256) {
        int d = ld_edge(ei, is64, N_EDGES + e0 + i);
        atomicAdd(&hist[d >> BSHIFT], 1);
    }
    __syncthreads();
    // scan histogram (512-slot Hillis-Steele)
    sc[t]       = (t < NBUCK)       ? hist[t]       : 0;
    sc[t + 256] = (t + 256 < NBUCK) ? hist[t + 256] : 0;
    __syncthreads();
    for (int off = 1; off < 512; off <<= 1) {
        int a0 = (t >= off) ? sc[t - off] : 0;
        int a1 = sc[t + 256 - off];
        __syncthreads();
        sc[t] += a0; sc[t + 256] += a1;
        __syncthreads();
    }
    for (int i = t; i < NBUCK; i += 256) {
        int excl = sc[i] - hist[i];
        pref[i] = excl;
        cur[i] = excl;
    }
    if (t == 0) pref[NBUCK] = n;
    __syncthreads();
    // pass B: scatter packed (local_d<<18 | src) into LDS stage, bucket-grouped
    for (int i = t; i < n; i += 256) {
        int s = ld_edge(ei, is64, e0 + i);
        int d = ld_edge(ei, is64, N_EDGES + e0 + i);
        int bk = d >> BSHIFT;
        int p = atomicAdd(&cur[bk], 1);
        stage[p] = ((unsigned int)(d & 511) << 18) | (unsigned int)s;
    }
    __syncthreads();
    // reserve global ranges, one atomic per non-empty bucket
    for (int i = t; i < NBUCK; i += 256) {
        int c = hist[i];
        gb[i] = c ? atomicAdd(&bucketCursor[i], c) : 0;
    }
    __syncthreads();
    // write out contiguous runs (binary-search bucket per slot)
    for (int p = t; p < n; p += 256) {
        int lo = 0, hi = NBUCK;
        while (hi - lo > 1) {
            int mid = (lo + hi) >> 1;
            if (pref[mid] <= p) lo = mid; else hi = mid;
        }
        bin[gb[lo] + (p - pref[lo])] = stage[p];
    }
}

// level-2: one block per bucket. Sort edges by node in LDS, write back
// sorted src IN PLACE, plus rowptr and dinv (degrees come free here).
__global__ void __launch_bounds__(256)
k_bucketsort(const int* __restrict__ bucketBase, unsigned int* __restrict__ bin,
             int* __restrict__ rowptr, float* __restrict__ dinv) {
    __shared__ int cnt[512];
    __shared__ int sc[512];
    __shared__ int cur[512];
    __shared__ unsigned int payload[MAXBUCK];
    int b = blockIdx.x, t = threadIdx.x;
    int base = bucketBase[b], end = bucketBase[b + 1];
    int n = end - base;
    cnt[t] = 0; cnt[t + 256] = 0;
    __syncthreads();
    // pass A: per-node local degree
    for (int i = t; i < n; i += 256) {
        unsigned int u = bin[base + i];
        atomicAdd(&cnt[u >> 18], 1);
    }
    __syncthreads();
    // scan 512
    sc[t] = cnt[t]; sc[t + 256] = cnt[t + 256];
    __syncthreads();
    for (int off = 1; off < 512; off <<= 1) {
        int a0 = (t >= off) ? sc[t - off] : 0;
        int a1 = sc[t + 256 - off];
        __syncthreads();
        sc[t] += a0; sc[t + 256] += a1;
        __syncthreads();
    }
    cur[t] = sc[t] - cnt[t];
    cur[t + 256] = sc[t + 256] - cnt[t + 256];
    __syncthreads();
    // pass B: scatter src into LDS by final local position
    for (int i = t; i < n; i += 256) {
        unsigned int u = bin[base + i];
        int ld = u >> 18;
        int p = atomicAdd(&cur[ld], 1);
        if (p < MAXBUCK) payload[p] = u & 0x3FFFFu;
    }
    __syncthreads();
    // coalesced in-place write-back of sorted src
    for (int i = t; i < n; i += 256) bin[base + i] = payload[i];
    // rowptr + dinv for this bucket's nodes
    int node0 = b << BSHIFT;
#pragma unroll
    for (int k = 0; k < 2; ++k) {
        int ld = t + k * 256;
        int node = node0 + ld;
        if (node < N_NODES) {
            rowptr[node] = base + (sc[ld] - cnt[ld]);
            dinv[node] = rsqrtf((float)cnt[ld] + 1.0f);
        }
    }
    if (b == 0 && t == 0) rowptr[N_NODES] = N_EDGES;
}

// h = x @ W  (row-major x: [N, FIN], W: [FIN, FOUT])
template <int FIN, int FOUT>
__global__ void k_xw(const float* __restrict__ x, const float* __restrict__ W,
                     float* __restrict__ h) {
    __shared__ float sW[FIN * FOUT];
    int t = threadIdx.x;
    if (t < FIN * FOUT) sW[t] = W[t];
    __syncthreads();
    int i = blockIdx.x * blockDim.x + t;
    if (i >= N_NODES) return;
    float xi[FIN];
#pragma unroll
    for (int k = 0; k < FIN; ++k) xi[k] = x[i * FIN + k];
#pragma unroll
    for (int j = 0; j < FOUT; ++j) {
        float acc = 0.f;
#pragma unroll
        for (int k = 0; k < FIN; ++k) acc += xi[k] * sW[k * FOUT + j];
        h[i * FOUT + j] = acc;
    }
}

// 16 lanes per node, lane = feature. Atomic-free CSR gather.
template <int F, bool RELU>
__global__ void k_agg(const int* __restrict__ rowptr, const unsigned int* __restrict__ esrc,
                      const float* __restrict__ dinv, const float* __restrict__ h,
                      const float* __restrict__ bias, float* __restrict__ out) {
    int tid = blockIdx.x * blockDim.x + threadIdx.x;
    int g = tid >> 4;       // node
    int f = tid & 15;       // feature lane
    if (g >= N_NODES) return;
    float di = dinv[g];
    int e0 = rowptr[g], e1 = rowptr[g + 1];
    float acc = 0.f;
    for (int e = e0; e < e1; ++e) {
        int s = (int)esrc[e];
        float nrm = dinv[s] * di;
        if (f < F) acc += nrm * h[s * F + f];
    }
    if (f < F) {
        float r = acc + di * di * h[g * F + f] + bias[f];
        if (RELU) r = fmaxf(r, 0.f);
        out[g * F + f] = r;
    }
}

extern "C" void kernel_launch(void* const* d_in, const int* in_sizes, int n_in,
                              void* d_out, int out_size, void* d_ws, size_t ws_size,
                              hipStream_t stream) {
    const float* x  = (const float*)d_in[0];
    const void*  ei = d_in[1];
    const float* W1 = (const float*)d_in[2];
    const float* b1 = (const float*)d_in[3];
    const float* W2 = (const float*)d_in[4];
    const float* b2 = (const float*)d_in[5];
    const float* W3 = (const float*)d_in[6];
    const float* b3 = (const float*)d_in[7];
    float* out = (float*)d_out;

    char* w = (char*)d_ws;
    int*   bucketCnt    = (int*)(w + 0);        //  2048 B (512 ints, zeroed)
    int*   bucketBase   = (int*)(w + 2048);     //  2048 B
    int*   bucketCursor = (int*)(w + 4096);     //  2048 B
    int*   flag         = (int*)(w + 6144);     //    64 B
    float* dinv         = (float*)(w + 6208);   //  800000 B
    int*   rowptr       = (int*)(w + 806208);   //  800064 B (200001 ints)
    unsigned int* bin   = (unsigned int*)(w + 1606272); // 25600000 B
    float* hbuf         = (float*)(w + 27206272);       // 12800000 B
    float* gbuf         = (float*)(w + 40006272);       //  8800000 B
    // total ~48.8 MB

    // ---- build degree + sorted CSR (shared across all 3 layers) ----
    k_zero<<<2, 256, 0, stream>>>(bucketCnt, 512);
    k_detect<<<1, 256, 0, stream>>>((const unsigned int*)ei, flag);
    k_hist<<<1024, 256, 0, stream>>>(ei, flag, bucketCnt);
    k_scan_buckets<<<1, 256, 0, stream>>>(bucketCnt, bucketBase, bucketCursor);
    k_binscatter<<<NCHUNK, 256, 0, stream>>>(ei, flag, bucketCursor, bin);
    k_bucketsort<<<NBUCK, 256, 0, stream>>>(bucketBase, bin, rowptr, dinv);

    // ---- layer 1: relu(gcn(x, W1, b1)) ----
    k_xw<11, 11><<<782, 256, 0, stream>>>(x, W1, hbuf);
    k_agg<11, true><<<12500, 256, 0, stream>>>(rowptr, bin, dinv, hbuf, b1, gbuf);
    // ---- layer 2: relu(gcn(g, W2, b2)) ----
    k_xw<11, 11><<<782, 256, 0, stream>>>(gbuf, W2, hbuf);
    k_agg<11, true><<<12500, 256, 0, stream>>>(rowptr, bin, dinv, hbuf, b2, gbuf);
    // ---- layer 3: gcn(g, W3, b3) ----
    k_xw<11, 16><<<782, 256, 0, stream>>>(gbuf, W3, hbuf);
    k_agg<16, false><<<12500, 256, 0, stream>>>(rowptr, bin, dinv, hbuf, b3, out);
}